// Round 15
// baseline (164.469 us; speedup 1.0000x reference)
//
#include <hip/hip_runtime.h>
#include <cstdint>
#include <cstddef>

#define N_HEADS 16

typedef __attribute__((ext_vector_type(4))) float f32x4;
typedef __attribute__((ext_vector_type(8))) short bf16x8;

// ---------------------------------------------------------------------------
// fp32 -> (hi, lo) bf16 split helpers (RTN-even, no NaN inputs).
// ---------------------------------------------------------------------------
static __device__ inline ushort f2bf(float x) {
    uint32_t u = __float_as_uint(x);
    uint32_t r = (u + 0x7fffu + ((u >> 16) & 1u)) >> 16;
    return (ushort)r;
}
static __device__ inline float bf2f(ushort h) {
    return __uint_as_float(((uint32_t)h) << 16);
}
static __device__ inline uint32_t cvt_pk_bf16(float lo, float hi) {
    uint32_t r;
    asm("v_cvt_pk_bf16_f32 %0, %1, %2" : "=v"(r) : "v"(lo), "v"(hi));
    return r;
}
// Raw v_exp_f32 (2^x). Inputs are bounded (|x| < ~30) so the OCML denorm
// fixup path is unnecessary; correctness-safe per learn_hip m214-v48.
static __device__ inline float exp2_raw(float x) {
    float r;
    asm("v_exp_f32 %0, %1" : "=v"(r) : "v"(x));
    return r;
}

// ---------------------------------------------------------------------------
// One launch for ALL splits. blockIdx.y segments:
// 0: query -> hi   1: keyv -> hi
// 2: wq -> hi      3: wk -> hi    4: wv -> hi    5: wo -> hi+lo
// ---------------------------------------------------------------------------
__global__ __launch_bounds__(256) void split_all(
    const float* __restrict__ query, const float* __restrict__ keyv,
    const float* __restrict__ wq, const float* __restrict__ wk,
    const float* __restrict__ wv, const float* __restrict__ wo,
    ushort* __restrict__ inq_h, ushort* __restrict__ inkv_h,
    ushort* __restrict__ wqh, ushort* __restrict__ wkh,
    ushort* __restrict__ wvh, ushort* __restrict__ woh,
    ushort* __restrict__ wol) {
    const float* x;
    ushort* hi;
    ushort* lo = nullptr;
    int n4;
    switch (blockIdx.y) {
        case 0: x = query; hi = inq_h;           n4 = 1048576; break;
        case 1: x = keyv;  hi = inkv_h;          n4 = 2097152; break;
        case 2: x = wq;    hi = wqh;             n4 = 262144;  break;
        case 3: x = wk;    hi = wkh;             n4 = 262144;  break;
        case 4: x = wv;    hi = wvh;             n4 = 262144;  break;
        default: x = wo;   hi = woh; lo = wol;   n4 = 262144;  break;
    }
    const int stride = gridDim.x * blockDim.x;
    const bool wlo = (lo != nullptr);
    for (int i = blockIdx.x * blockDim.x + threadIdx.x; i < n4; i += stride) {
        const float4 v = reinterpret_cast<const float4*>(x)[i];
        ushort4 h;
        h.x = f2bf(v.x); h.y = f2bf(v.y); h.z = f2bf(v.z); h.w = f2bf(v.w);
        reinterpret_cast<ushort4*>(hi)[i] = h;
        if (wlo) {
            ushort4 l;
            l.x = f2bf(v.x - bf2f(h.x)); l.y = f2bf(v.y - bf2f(h.y));
            l.z = f2bf(v.z - bf2f(h.z)); l.w = f2bf(v.w - bf2f(h.w));
            reinterpret_cast<ushort4*>(lo)[i] = l;
        }
    }
}

#define BM 128
#define BN 128
#define BK 32

#define GLD_LDS16(gp, lp)                                                  \
    __builtin_amdgcn_global_load_lds(                                      \
        (const __attribute__((address_space(1))) void*)(gp),               \
        (__attribute__((address_space(3))) void*)(lp), 16, 0, 0)

// ---------------------------------------------------------------------------
// Batched Q/K/V projection, single launch (640 blocks), all 1-pass hi*hi.
// Round 15: 256x128 block tile, per-wave 64x128 output (4 A-frags x 8
// B-frags = 12 ds_read_b128 per 32 MFMA vs 8 per 16) — the kernel is
// LDS-read-throughput-bound, so output per LDS-cycle rises ~33%.
// 2-barrier single-buffer loop (dbuf was neutral, m99/m100-consistent).
// launch_bounds(256,2): acc=128 VGPR + ~70 misc < 256-reg cap (no spill).
//   [0,128)   seg 0: Q = inq_h  @ wq^T, scaled -> attn Q layout [bh][x][64]
//   [128,384) seg 1: K = inkv_h @ wk^T -> attn K layout
//   [384,640) seg 2: V = inkv_h @ wv^T -> attn V^T layout [bh][dd][2048]
// Per-segment bijective XCD-grouping for weight/A-panel L2 residency.
// ---------------------------------------------------------------------------
#define QBM 256
#define QBN 128
__global__ __launch_bounds__(256, 2) void qkv_proj(
    const ushort* __restrict__ Aq, const ushort* __restrict__ Akv,
    const ushort* __restrict__ Wqh, const ushort* __restrict__ Wkh,
    const ushort* __restrict__ Wvh, ushort* __restrict__ aq,
    ushort* __restrict__ ak, ushort* __restrict__ avt) {
    constexpr int K = 1024;
    constexpr float QSCALE = 0.18033688011112042f;  // 0.125 * log2(e)
    __shared__ ushort sA[QBM * BK];  // 16 KB
    __shared__ ushort sB[QBN * BK];  // 8 KB

    const int bid = blockIdx.x;
    int seg, local, nxcd;
    if (bid < 128)      { seg = 0; local = bid;       nxcd = 16; }
    else if (bid < 384) { seg = 1; local = bid - 128; nxcd = 32; }
    else                { seg = 2; local = bid - 384; nxcd = 32; }
    // XCD-grouped bijection within segment (segment size % 8 == 0).
    local = (local & 7) * nxcd + (local >> 3);
    const int n0 = (local & 7) * QBN;
    const int m0 = (local >> 3) * QBM;

    const ushort* A  = (seg == 0) ? Aq : Akv;
    const ushort* Wh = (seg == 0) ? Wqh : (seg == 1 ? Wkh : Wvh);

    const int tid = threadIdx.x;
    const int lane = tid & 63;
    const int w = tid >> 6;
    const int wm = w * 64;  // wave's 64 output rows

    // A staging: wave w covers rows [w*64, w*64+64) = 4 chunks of 16 rows.
    int sarow[4], sakq[4];
#pragma unroll
    for (int c = 0; c < 4; ++c) {
        const int row = (w * 4 + c) * 16 + (lane >> 2);
        sarow[c] = row;
        sakq[c] = (((lane & 3) ^ ((row >> 1) & 3)) << 3);
    }
    // B staging: wave w covers 2 chunks of 16 rows (128 rows total).
    int sbrow[2], sbkq[2];
#pragma unroll
    for (int c = 0; c < 2; ++c) {
        const int row = (w * 2 + c) * 16 + (lane >> 2);
        sbrow[c] = row;
        sbkq[c] = (((lane & 3) ^ ((row >> 1) & 3)) << 3);
    }

    f32x4 acc[4][8];
#pragma unroll
    for (int i = 0; i < 4; ++i)
#pragma unroll
        for (int j = 0; j < 8; ++j) acc[i][j] = (f32x4)0.0f;

    const int lr = lane & 15;
    const int kq = lane >> 4;

    for (int k0 = 0; k0 < K; k0 += BK) {
#pragma unroll
        for (int c = 0; c < 4; ++c)
            GLD_LDS16(A + (size_t)(m0 + sarow[c]) * K + k0 + sakq[c],
                      &sA[(w * 4 + c) * 512]);
#pragma unroll
        for (int c = 0; c < 2; ++c)
            GLD_LDS16(Wh + (size_t)(n0 + sbrow[c]) * K + k0 + sbkq[c],
                      &sB[(w * 2 + c) * 512]);
        __syncthreads();

        bf16x8 afh[4], bfh[8];
#pragma unroll
        for (int f = 0; f < 4; ++f) {
            const int arow = wm + f * 16 + lr;
            afh[f] = *reinterpret_cast<const bf16x8*>(
                &sA[arow * 32 + ((kq ^ ((arow >> 1) & 3)) << 3)]);
        }
#pragma unroll
        for (int j = 0; j < 8; ++j) {
            const int brow = j * 16 + lr;
            bfh[j] = *reinterpret_cast<const bf16x8*>(
                &sB[brow * 32 + ((kq ^ ((brow >> 1) & 3)) << 3)]);
        }
#pragma unroll
        for (int i = 0; i < 4; ++i)
#pragma unroll
            for (int j = 0; j < 8; ++j)
                acc[i][j] = __builtin_amdgcn_mfma_f32_16x16x32_bf16(
                    afh[i], bfh[j], acc[i][j], 0, 0, 0);
        __syncthreads();
    }

    const int cr = (lane >> 4) << 2;
    const int cc = lane & 15;

    if (seg < 2) {  // Q / K layout: [bh][x][64] hi-only, dd ^ ((x&7)<<3)
        const int log2X = (seg == 0) ? 10 : 11;
        const float scale = (seg == 0) ? QSCALE : 1.0f;
        ushort* out = (seg == 0) ? aq : ak;
        const int xm = (1 << log2X) - 1;
#pragma unroll
        for (int i = 0; i < 4; ++i)
#pragma unroll
            for (int j = 0; j < 8; ++j) {
                const int col = n0 + j * 16 + cc;
                const int h = col >> 6, dd = col & 63;
#pragma unroll
                for (int r = 0; r < 4; ++r) {
                    const int mr = m0 + wm + i * 16 + cr + r;
                    const int bb = mr >> log2X;
                    const int x = mr & xm;
                    out[(((size_t)(bb * N_HEADS + h) << log2X) + x) * 64 +
                        (dd ^ ((x & 7) << 3))] = f2bf(acc[i][j][r] * scale);
                }
            }
    } else {  // V^T layout: [bh][dd][2048], s swizzled within 64-blocks
#pragma unroll
        for (int i = 0; i < 4; ++i)
#pragma unroll
            for (int j = 0; j < 8; ++j) {
                const int col = n0 + j * 16 + cc;
                const int h = col >> 6, dd = col & 63;
                const int sb = m0 + wm + i * 16 + cr;
                const int bb = sb >> 11;
                const int sx = sb & 2047;
                ushort4 hv;
#pragma unroll
                for (int r = 0; r < 4; ++r)
                    ((ushort*)&hv)[r] = f2bf(acc[i][j][r]);
                const size_t pos =
                    ((size_t)(bb * N_HEADS + h) * 64 + dd) * 2048 +
                    (sx & ~63) + ((sx & 63) ^ ((dd & 7) << 3));
                *reinterpret_cast<ushort4*>(&avt[pos]) = hv;
            }
    }
}

// ---------------------------------------------------------------------------
// O-projection GEMM: out = AO[M,K] * wo[N,K]^T, 2-pass (A_hi*(W_hi+W_lo)).
// 64x128 tiles, 512 blocks (2/CU), 1-barrier dbuf K-loop (round 14).
// ---------------------------------------------------------------------------
#define OBM 64
__global__ __launch_bounds__(256, 2) void gemm_oproj(
    const ushort* __restrict__ Ahi, const ushort* __restrict__ Whi,
    const ushort* __restrict__ Wlo, float* __restrict__ Cf, int M, int N,
    int K) {
    __shared__ ushort sA[2][OBM * BK];     // 4 KB x2
    __shared__ ushort sB[2][2][BN * BK];   // [buf][hi/lo], 8 KB each

    const int tid = threadIdx.x;
    const int lane = tid & 63;
    const int w = tid >> 6;
    const int m0 = blockIdx.y * OBM;
    const int n0 = blockIdx.x * BN;
    const int NT = K / BK;

    // A staging: wave w covers rows [w*16, w*16+16).
    const int sarow = w * 16 + (lane >> 2);
    const int saq = (((lane & 3) ^ ((sarow >> 1) & 3)) << 3);
    // B staging: wave w covers 2 chunks of 16 rows.
    int srow[2], skq[2];
#pragma unroll
    for (int c = 0; c < 2; ++c) {
        const int row = (w * 2 + c) * 16 + (lane >> 2);
        srow[c] = row;
        skq[c] = (((lane & 3) ^ ((row >> 1) & 3)) << 3);
    }

    auto stage = [&](int buf, int k0) {
        GLD_LDS16(Ahi + (size_t)(m0 + sarow) * K + k0 + saq,
                  &sA[buf][w * 512]);
#pragma unroll
        for (int c = 0; c < 2; ++c) {
            const size_t gb = (size_t)(n0 + srow[c]) * K + k0 + skq[c];
            const int loff = (w * 2 + c) * 512;
            GLD_LDS16(Whi + gb, &sB[buf][0][loff]);
            GLD_LDS16(Wlo + gb, &sB[buf][1][loff]);
        }
    };

    f32x4 acc[8];
#pragma unroll
    for (int j = 0; j < 8; ++j) acc[j] = (f32x4)0.0f;

    const int lr = lane & 15;
    const int kq = lane >> 4;

    stage(0, 0);
    __syncthreads();

    for (int t = 0; t < NT; ++t) {
        const int bi = t & 1;
        if (t + 1 < NT) stage(bi ^ 1, (t + 1) * BK);

        const int arow = w * 16 + lr;
        const bf16x8 afh = *reinterpret_cast<const bf16x8*>(
            &sA[bi][arow * 32 + ((kq ^ ((arow >> 1) & 3)) << 3)]);
#pragma unroll
        for (int j = 0; j < 8; ++j) {
            const int brow = j * 16 + lr;
            const int boff = brow * 32 + ((kq ^ ((brow >> 1) & 3)) << 3);
            const bf16x8 bfh =
                *reinterpret_cast<const bf16x8*>(&sB[bi][0][boff]);
            const bf16x8 bfl =
                *reinterpret_cast<const bf16x8*>(&sB[bi][1][boff]);
            acc[j] = __builtin_amdgcn_mfma_f32_16x16x32_bf16(afh, bfh,
                                                             acc[j], 0, 0, 0);
            acc[j] = __builtin_amdgcn_mfma_f32_16x16x32_bf16(afh, bfl,
                                                             acc[j], 0, 0, 0);
        }
        __syncthreads();
    }

    const int cr = (lane >> 4) << 2;
    const int cc = lane & 15;
#pragma unroll
    for (int j = 0; j < 8; ++j) {
        float* cp = &Cf[(size_t)(m0 + w * 16 + cr) * N + n0 + j * 16 + cc];
#pragma unroll
        for (int r = 0; r < 4; ++r) cp[(size_t)r * N] = acc[j][r];
    }
}

// ---------------------------------------------------------------------------
// MFMA flash attention, max-free softmax (unchanged from round 11/13).
// ---------------------------------------------------------------------------
__global__ __launch_bounds__(256, 4) void attn_mfma(
    const ushort* __restrict__ Qhi, const ushort* __restrict__ Khi,
    const ushort* __restrict__ Vhi, ushort* __restrict__ Ohi) {
    constexpr int T = 1024, S = 2048, NT = S / 64;
    __shared__ ushort sK[2][4096];  // [buf][s*64+dd]  (hi)
    __shared__ ushort sV[2][4096];  // [buf][dd*64+s]  (hi)
    __shared__ ushort sPb[4096];    // 4 x 2KB wave-private P buffers

    const int tid = threadIdx.x;
    const int lane = tid & 63;
    const int w = tid >> 6;
    const int id = blockIdx.x;
    const int wid = (id & 7) * 128 + (id >> 3);
    const int t0 = (wid & 15) * 64;
    const int bh = wid >> 4;
    const int lr = lane & 15;
    const int g = lane >> 4;
    const int swz = (lr & 7) << 3;

    const size_t qbase = ((size_t)bh * T + t0) * 64;
    const size_t kbase = (size_t)bh * S * 64;
    const size_t vbase = (size_t)bh * 64;

    // per-lane staging pointers (advance by constants per tile)
    int loff[2];
    const ushort* kp[2];
    const ushort* vp[2];
#pragma unroll
    for (int i = 0; i < 2; ++i) {
        loff[i] = i * 2048 + w * 512 + lane * 8;
        kp[i] = Khi + kbase + loff[i];
        vp[i] = Vhi + (vbase + (loff[i] >> 6)) * S + (loff[i] & 63);
    }

    // precomputed LDS offsets (K-read == V-read form), P write/read offsets
    int rdoff[4][2], pwoff[4], proff[2];
#pragma unroll
    for (int j = 0; j < 4; ++j) {
#pragma unroll
        for (int kk = 0; kk < 2; ++kk)
            rdoff[j][kk] = (j * 16 + lr) * 64 + ((kk * 32 + g * 8) ^ swz);
        pwoff[j] = lr * 64 + ((j * 16 + g * 4) ^ swz);
    }
#pragma unroll
    for (int kk = 0; kk < 2; ++kk)
        proff[kk] = lr * 64 + ((kk * 32 + g * 8) ^ swz);

    // prologue: Q-hi -> sK[1]; first K/V tile -> buf 0
#pragma unroll
    for (int i = 0; i < 2; ++i) GLD_LDS16(Qhi + qbase + loff[i], &sK[1][loff[i]]);
#pragma unroll
    for (int i = 0; i < 2; ++i) {
        GLD_LDS16(kp[i], &sK[0][loff[i]]);
        GLD_LDS16(vp[i], &sV[0][loff[i]]);
        kp[i] += 4096;
        vp[i] += 64;
    }
    __syncthreads();

    bf16x8 qf[2];
#pragma unroll
    for (int kk = 0; kk < 2; ++kk)
        qf[kk] = *reinterpret_cast<const bf16x8*>(
            &sK[1][(w * 16 + lr) * 64 + ((kk * 32 + g * 8) ^ swz)]);
    __syncthreads();  // all Q reads done before buf1 gets overwritten

    ushort* sP = &sPb[w * 1024];  // wave-private

    f32x4 oacc[4];
#pragma unroll
    for (int jd = 0; jd < 4; ++jd) oacc[jd] = (f32x4)0.0f;
    const f32x4 zero4 = (f32x4)0.0f;  // persistent C-in for QK chain starts
    float lpart = 0.0f;  // per-lane partial denominator (own 16 s-slots)

    for (int t = 0; t < NT; ++t) {
        const int bi = t & 1;
        if (t + 1 < NT) {
#pragma unroll
            for (int i = 0; i < 2; ++i) {
                GLD_LDS16(kp[i], &sK[bi ^ 1][loff[i]]);
                GLD_LDS16(vp[i], &sV[bi ^ 1][loff[i]]);
                kp[i] += 4096;
                vp[i] += 64;
            }
        }

        // ---- QK^T swapped, 1-pass: k_hi * q_hi (C-in = zero4) ----
        f32x4 sacc[4];
        __builtin_amdgcn_s_setprio(1);
#pragma unroll
        for (int j = 0; j < 4; ++j) {
            const bf16x8 kh0 = *reinterpret_cast<const bf16x8*>(
                &sK[bi][rdoff[j][0]]);
            const bf16x8 kh1 = *reinterpret_cast<const bf16x8*>(
                &sK[bi][rdoff[j][1]]);
            sacc[j] = __builtin_amdgcn_mfma_f32_16x16x32_bf16(
                kh0, qf[0], zero4, 0, 0, 0);
            sacc[j] = __builtin_amdgcn_mfma_f32_16x16x32_bf16(
                kh1, qf[1], sacc[j], 0, 0, 0);
        }
        __builtin_amdgcn_s_setprio(0);

        // ---- max-free softmax: p = exp2(logit); partial l; pack bf16 ----
        uint32_t wpk[4][2];
#pragma unroll
        for (int j = 0; j < 4; ++j) {
            const float p0 = exp2_raw(sacc[j][0]);
            const float p1 = exp2_raw(sacc[j][1]);
            const float p2 = exp2_raw(sacc[j][2]);
            const float p3 = exp2_raw(sacc[j][3]);
            lpart += (p0 + p1) + (p2 + p3);
            wpk[j][0] = cvt_pk_bf16(p0, p1);
            wpk[j][1] = cvt_pk_bf16(p2, p3);
        }

#pragma unroll
        for (int j = 0; j < 4; ++j)
            *reinterpret_cast<uint2*>(&sP[pwoff[j]]) =
                make_uint2(wpk[j][0], wpk[j][1]);
        asm volatile("s_waitcnt lgkmcnt(0)" ::: "memory");
        __builtin_amdgcn_sched_barrier(0);

        // ---- PV, 1-pass ----
        bf16x8 pf[2];
#pragma unroll
        for (int kk = 0; kk < 2; ++kk)
            pf[kk] = *reinterpret_cast<const bf16x8*>(&sP[proff[kk]]);
        __builtin_amdgcn_s_setprio(1);
#pragma unroll
        for (int jd = 0; jd < 4; ++jd) {
#pragma unroll
            for (int kk = 0; kk < 2; ++kk) {
                const bf16x8 vh = *reinterpret_cast<const bf16x8*>(
                    &sV[bi][rdoff[jd][kk]]);
                oacc[jd] = __builtin_amdgcn_mfma_f32_16x16x32_bf16(
                    pf[kk], vh, oacc[jd], 0, 0, 0);
            }
        }
        __builtin_amdgcn_s_setprio(0);
        __syncthreads();  // drains next tile's loads; protects dbuf reuse
    }

    // ---- epilogue: reduce l across g-groups, write O hi-only ----
    float l = lpart;
    l += __shfl_xor(l, 16);
    l += __shfl_xor(l, 32);

    const int b = bh >> 4, h = bh & 15;
    float linv[4];
#pragma unroll
    for (int r = 0; r < 4; ++r) linv[r] = 1.0f / __shfl(l, g * 4 + r);
#pragma unroll
    for (int r = 0; r < 4; ++r) {
        const int q = t0 + w * 16 + g * 4 + r;
        const size_t rowb = ((size_t)(b * T + q)) * 1024 + h * 64;
#pragma unroll
        for (int jd = 0; jd < 4; ++jd)
            Ohi[rowb + jd * 16 + lr] = f2bf(oacc[jd][r] * linv[r]);
    }
}

// ---------------------------------------------------------------------------
extern "C" void kernel_launch(void* const* d_in, const int* in_sizes, int n_in,
                              void* d_out, int out_size, void* d_ws, size_t ws_size,
                              hipStream_t stream) {
    const int B = 4, T = 1024, S = 2048, D = 1024;

    const float* query = (const float*)d_in[0];
    const float* keyv  = (const float*)d_in[1];
    const float* wq    = (const float*)d_in[2];
    const float* wk    = (const float*)d_in[3];
    const float* wv    = (const float*)d_in[4];
    const float* wo    = (const float*)d_in[5];
    float* out = (float*)d_out;

    const size_t nQ = (size_t)B * T * D;  // 4M
    const size_t nK = (size_t)B * S * D;  // 8M
    const size_t nW = (size_t)D * D;      // 1M

    uint8_t* p = (uint8_t*)d_ws;
    ushort* inq_h = (ushort*)p;  p += nQ * 2;   // 8 MB
    ushort* inkv_h = (ushort*)p; p += nK * 2;   // 16 MB
    ushort* wqh = (ushort*)p;    p += nW * 2;
    ushort* wkh = (ushort*)p;    p += nW * 2;
    ushort* wvh = (ushort*)p;    p += nW * 2;
    ushort* woh = (ushort*)p;    p += nW * 2;
    ushort* wol = (ushort*)p;    p += nW * 2;   // 10 MB
    ushort* aq_h = (ushort*)p;   p += nQ * 2;   // 8 MB (hi only)
    ushort* ak_h = (ushort*)p;   p += nK * 2;   // 16 MB (hi only)
    ushort* avt_h = (ushort*)p;  p += nK * 2;   // 16 MB (hi only)
    ushort* ao_h = (ushort*)p;   p += nQ * 2;   // 8 MB (hi only)
    // total 82 MB

    const dim3 blk(256);

    // 1) all input/weight splits, one launch
    split_all<<<dim3(512, 6), blk, 0, stream>>>(
        query, keyv, wq, wk, wv, wo, inq_h, inkv_h, wqh, wkh, wvh, woh, wol);

    // 2) Q/K/V projections: 256x128 tiles, per-wave 64x128 (640 blocks)
    qkv_proj<<<dim3(640), blk, 0, stream>>>(inq_h, inkv_h, wqh, wkh, wvh,
                                            aq_h, ak_h, avt_h);

    // 3) attention (1-D XCD-grouped grid; writes hi-only O)
    attn_mfma<<<dim3((T / 64) * B * N_HEADS), blk, 0, stream>>>(
        aq_h, ak_h, avt_h, ao_h);

    // 4) output projection, 2-pass, 64x128 tiles, dbuf K-loop
    gemm_oproj<<<dim3(D / BN, (B * T) / OBM), blk, 0, stream>>>(
        ao_h, woh, wol, out, B * T, D, D);
}

// Round 16
// 156.885 us; speedup vs baseline: 1.0483x; 1.0483x over previous
//
#include <hip/hip_runtime.h>
#include <cstdint>
#include <cstddef>

#define N_HEADS 16

typedef __attribute__((ext_vector_type(4))) float f32x4;
typedef __attribute__((ext_vector_type(8))) short bf16x8;

// ---------------------------------------------------------------------------
// fp32 -> (hi, lo) bf16 split helpers (RTN-even, no NaN inputs).
// ---------------------------------------------------------------------------
static __device__ inline ushort f2bf(float x) {
    uint32_t u = __float_as_uint(x);
    uint32_t r = (u + 0x7fffu + ((u >> 16) & 1u)) >> 16;
    return (ushort)r;
}
static __device__ inline float bf2f(ushort h) {
    return __uint_as_float(((uint32_t)h) << 16);
}
static __device__ inline uint32_t cvt_pk_bf16(float lo, float hi) {
    uint32_t r;
    asm("v_cvt_pk_bf16_f32 %0, %1, %2" : "=v"(r) : "v"(lo), "v"(hi));
    return r;
}
// Raw v_exp_f32 (2^x). Inputs are bounded (|x| < ~30) so the OCML denorm
// fixup path is unnecessary; correctness-safe per learn_hip m214-v48.
static __device__ inline float exp2_raw(float x) {
    float r;
    asm("v_exp_f32 %0, %1" : "=v"(r) : "v"(x));
    return r;
}

// ---------------------------------------------------------------------------
// One launch for ALL splits. blockIdx.y segments:
// 0: query -> hi   1: keyv -> hi
// 2: wq -> hi      3: wk -> hi    4: wv -> hi    5: wo -> hi+lo
// ---------------------------------------------------------------------------
__global__ __launch_bounds__(256) void split_all(
    const float* __restrict__ query, const float* __restrict__ keyv,
    const float* __restrict__ wq, const float* __restrict__ wk,
    const float* __restrict__ wv, const float* __restrict__ wo,
    ushort* __restrict__ inq_h, ushort* __restrict__ inkv_h,
    ushort* __restrict__ wqh, ushort* __restrict__ wkh,
    ushort* __restrict__ wvh, ushort* __restrict__ woh,
    ushort* __restrict__ wol) {
    const float* x;
    ushort* hi;
    ushort* lo = nullptr;
    int n4;
    switch (blockIdx.y) {
        case 0: x = query; hi = inq_h;           n4 = 1048576; break;
        case 1: x = keyv;  hi = inkv_h;          n4 = 2097152; break;
        case 2: x = wq;    hi = wqh;             n4 = 262144;  break;
        case 3: x = wk;    hi = wkh;             n4 = 262144;  break;
        case 4: x = wv;    hi = wvh;             n4 = 262144;  break;
        default: x = wo;   hi = woh; lo = wol;   n4 = 262144;  break;
    }
    const int stride = gridDim.x * blockDim.x;
    const bool wlo = (lo != nullptr);
    for (int i = blockIdx.x * blockDim.x + threadIdx.x; i < n4; i += stride) {
        const float4 v = reinterpret_cast<const float4*>(x)[i];
        ushort4 h;
        h.x = f2bf(v.x); h.y = f2bf(v.y); h.z = f2bf(v.z); h.w = f2bf(v.w);
        reinterpret_cast<ushort4*>(hi)[i] = h;
        if (wlo) {
            ushort4 l;
            l.x = f2bf(v.x - bf2f(h.x)); l.y = f2bf(v.y - bf2f(h.y));
            l.z = f2bf(v.z - bf2f(h.z)); l.w = f2bf(v.w - bf2f(h.w));
            reinterpret_cast<ushort4*>(lo)[i] = l;
        }
    }
}

#define BM 128
#define BN 128
#define BK 32

#define GLD_LDS16(gp, lp)                                                  \
    __builtin_amdgcn_global_load_lds(                                      \
        (const __attribute__((address_space(1))) void*)(gp),               \
        (__attribute__((address_space(3))) void*)(lp), 16, 0, 0)

// ---------------------------------------------------------------------------
// Batched Q/K/V projection, single launch (1280 blocks), all 1-pass hi*hi.
// Round-13 configuration (measured best): 128x128 tile, single-buffer
// 2-barrier K-loop, launch_bounds(256,3) (reg cap ~170, no spill).
//   [0,256)   seg 0: Q = inq_h  @ wq^T, scaled -> attn Q layout [bh][x][64]
//   [256,768) seg 1: K = inkv_h @ wk^T -> attn K layout
//   [768,1280)seg 2: V = inkv_h @ wv^T -> attn V^T layout [bh][dd][2048]
// Per-segment bijective XCD-grouping for A-panel L2 residency.
// ---------------------------------------------------------------------------
__global__ __launch_bounds__(256, 3) void qkv_proj(
    const ushort* __restrict__ Aq, const ushort* __restrict__ Akv,
    const ushort* __restrict__ Wqh, const ushort* __restrict__ Wkh,
    const ushort* __restrict__ Wvh, ushort* __restrict__ aq,
    ushort* __restrict__ ak, ushort* __restrict__ avt) {
    constexpr int K = 1024;
    constexpr float QSCALE = 0.18033688011112042f;  // 0.125 * log2(e)
    __shared__ ushort sA[BM * BK];
    __shared__ ushort sB[BN * BK];

    const int bid = blockIdx.x;
    int seg, local, nrow;
    if (bid < 256)      { seg = 0; local = bid;       nrow = 32; }
    else if (bid < 768) { seg = 1; local = bid - 256; nrow = 64; }
    else                { seg = 2; local = bid - 768; nrow = 64; }
    // XCD-grouped bijection within segment (segment size % 8 == 0).
    local = (local & 7) * nrow + (local >> 3);
    const int n0 = (local & 7) * BN;
    const int m0 = (local >> 3) * BM;

    const ushort* A  = (seg == 0) ? Aq : Akv;
    const ushort* Wh = (seg == 0) ? Wqh : (seg == 1 ? Wkh : Wvh);

    const int tid = threadIdx.x;
    const int lane = tid & 63;
    const int w = tid >> 6;
    const int wm = (w >> 1) * 64;
    const int wn = (w & 1) * 64;

    int srow[2], skq[2];
#pragma unroll
    for (int c = 0; c < 2; ++c) {
        const int row = (w * 2 + c) * 16 + (lane >> 2);
        srow[c] = row;
        skq[c] = (((lane & 3) ^ ((row >> 1) & 3)) << 3);
    }

    f32x4 acc[4][4];
#pragma unroll
    for (int i = 0; i < 4; ++i)
#pragma unroll
        for (int j = 0; j < 4; ++j) acc[i][j] = (f32x4)0.0f;

    const int lr = lane & 15;
    const int kq = lane >> 4;

    for (int k0 = 0; k0 < K; k0 += BK) {
#pragma unroll
        for (int c = 0; c < 2; ++c) {
            const size_t ga = (size_t)(m0 + srow[c]) * K + k0 + skq[c];
            const size_t gb = (size_t)(n0 + srow[c]) * K + k0 + skq[c];
            const int loff = (w * 2 + c) * 512;
            GLD_LDS16(A + ga, &sA[loff]);
            GLD_LDS16(Wh + gb, &sB[loff]);
        }
        __syncthreads();

        bf16x8 afh[4], bfh[4];
#pragma unroll
        for (int f = 0; f < 4; ++f) {
            const int arow = wm + f * 16 + lr;
            afh[f] = *reinterpret_cast<const bf16x8*>(
                &sA[arow * 32 + ((kq ^ ((arow >> 1) & 3)) << 3)]);
            const int brow = wn + f * 16 + lr;
            bfh[f] = *reinterpret_cast<const bf16x8*>(
                &sB[brow * 32 + ((kq ^ ((brow >> 1) & 3)) << 3)]);
        }
#pragma unroll
        for (int i = 0; i < 4; ++i)
#pragma unroll
            for (int j = 0; j < 4; ++j)
                acc[i][j] = __builtin_amdgcn_mfma_f32_16x16x32_bf16(
                    afh[i], bfh[j], acc[i][j], 0, 0, 0);
        __syncthreads();
    }

    const int cr = (lane >> 4) << 2;
    const int cc = lane & 15;

    if (seg < 2) {  // Q / K layout: [bh][x][64] hi-only, dd ^ ((x&7)<<3)
        const int log2X = (seg == 0) ? 10 : 11;
        const float scale = (seg == 0) ? QSCALE : 1.0f;
        ushort* out = (seg == 0) ? aq : ak;
        const int xm = (1 << log2X) - 1;
#pragma unroll
        for (int i = 0; i < 4; ++i)
#pragma unroll
            for (int j = 0; j < 4; ++j) {
                const int col = n0 + wn + j * 16 + cc;
                const int h = col >> 6, dd = col & 63;
#pragma unroll
                for (int r = 0; r < 4; ++r) {
                    const int mr = m0 + wm + i * 16 + cr + r;
                    const int bb = mr >> log2X;
                    const int x = mr & xm;
                    out[(((size_t)(bb * N_HEADS + h) << log2X) + x) * 64 +
                        (dd ^ ((x & 7) << 3))] = f2bf(acc[i][j][r] * scale);
                }
            }
    } else {  // V^T layout: [bh][dd][2048], s swizzled within 64-blocks
#pragma unroll
        for (int i = 0; i < 4; ++i)
#pragma unroll
            for (int j = 0; j < 4; ++j) {
                const int col = n0 + wn + j * 16 + cc;
                const int h = col >> 6, dd = col & 63;
                const int sb = m0 + wm + i * 16 + cr;
                const int bb = sb >> 11;
                const int sx = sb & 2047;
                ushort4 hv;
#pragma unroll
                for (int r = 0; r < 4; ++r)
                    ((ushort*)&hv)[r] = f2bf(acc[i][j][r]);
                const size_t pos =
                    ((size_t)(bb * N_HEADS + h) * 64 + dd) * 2048 +
                    (sx & ~63) + ((sx & 63) ^ ((dd & 7) << 3));
                *reinterpret_cast<ushort4*>(&avt[pos]) = hv;
            }
    }
}

// ---------------------------------------------------------------------------
// O-projection GEMM: out = AO[M,K] * wo[N,K]^T, 2-pass (A_hi*(W_hi+W_lo)).
// 64x128 tiles -> 512 blocks (2/CU), single-buffer 2-barrier K-loop
// (round-13 configuration). Wave w owns rows [w*16,+16) x 128 cols.
// ---------------------------------------------------------------------------
#define OBM 64
__global__ __launch_bounds__(256, 2) void gemm_oproj(
    const ushort* __restrict__ Ahi, const ushort* __restrict__ Whi,
    const ushort* __restrict__ Wlo, float* __restrict__ Cf, int M, int N,
    int K) {
    __shared__ ushort sA[OBM * BK];    // 4 KB
    __shared__ ushort sB[2][BN * BK];  // 16 KB

    const int tid = threadIdx.x;
    const int lane = tid & 63;
    const int w = tid >> 6;
    const int m0 = blockIdx.y * OBM;
    const int n0 = blockIdx.x * BN;

    // A staging: wave w covers rows [w*16, w*16+16).
    const int sarow = w * 16 + (lane >> 2);
    const int saq = (((lane & 3) ^ ((sarow >> 1) & 3)) << 3);
    // B staging: wave w covers 2 chunks of 16 rows.
    int srow[2], skq[2];
#pragma unroll
    for (int c = 0; c < 2; ++c) {
        const int row = (w * 2 + c) * 16 + (lane >> 2);
        srow[c] = row;
        skq[c] = (((lane & 3) ^ ((row >> 1) & 3)) << 3);
    }

    f32x4 acc[8];
#pragma unroll
    for (int j = 0; j < 8; ++j) acc[j] = (f32x4)0.0f;

    const int lr = lane & 15;
    const int kq = lane >> 4;

    for (int k0 = 0; k0 < K; k0 += BK) {
        GLD_LDS16(Ahi + (size_t)(m0 + sarow) * K + k0 + saq, &sA[w * 512]);
#pragma unroll
        for (int c = 0; c < 2; ++c) {
            const size_t gb = (size_t)(n0 + srow[c]) * K + k0 + skq[c];
            const int loff = (w * 2 + c) * 512;
            GLD_LDS16(Whi + gb, &sB[0][loff]);
            GLD_LDS16(Wlo + gb, &sB[1][loff]);
        }
        __syncthreads();

        const int arow = w * 16 + lr;
        const bf16x8 afh = *reinterpret_cast<const bf16x8*>(
            &sA[arow * 32 + ((kq ^ ((arow >> 1) & 3)) << 3)]);
#pragma unroll
        for (int j = 0; j < 8; ++j) {
            const int brow = j * 16 + lr;
            const int boff = brow * 32 + ((kq ^ ((brow >> 1) & 3)) << 3);
            const bf16x8 bfh = *reinterpret_cast<const bf16x8*>(&sB[0][boff]);
            const bf16x8 bfl = *reinterpret_cast<const bf16x8*>(&sB[1][boff]);
            acc[j] = __builtin_amdgcn_mfma_f32_16x16x32_bf16(afh, bfh,
                                                             acc[j], 0, 0, 0);
            acc[j] = __builtin_amdgcn_mfma_f32_16x16x32_bf16(afh, bfl,
                                                             acc[j], 0, 0, 0);
        }
        __syncthreads();
    }

    const int cr = (lane >> 4) << 2;
    const int cc = lane & 15;
#pragma unroll
    for (int j = 0; j < 8; ++j) {
        float* cp = &Cf[(size_t)(m0 + w * 16 + cr) * N + n0 + j * 16 + cc];
#pragma unroll
        for (int r = 0; r < 4; ++r) cp[(size_t)r * N] = acc[j][r];
    }
}

// ---------------------------------------------------------------------------
// MFMA flash attention, max-free softmax (round-11 version, unchanged).
// ---------------------------------------------------------------------------
__global__ __launch_bounds__(256, 4) void attn_mfma(
    const ushort* __restrict__ Qhi, const ushort* __restrict__ Khi,
    const ushort* __restrict__ Vhi, ushort* __restrict__ Ohi) {
    constexpr int T = 1024, S = 2048, NT = S / 64;
    __shared__ ushort sK[2][4096];  // [buf][s*64+dd]  (hi)
    __shared__ ushort sV[2][4096];  // [buf][dd*64+s]  (hi)
    __shared__ ushort sPb[4096];    // 4 x 2KB wave-private P buffers

    const int tid = threadIdx.x;
    const int lane = tid & 63;
    const int w = tid >> 6;
    const int id = blockIdx.x;
    const int wid = (id & 7) * 128 + (id >> 3);
    const int t0 = (wid & 15) * 64;
    const int bh = wid >> 4;
    const int lr = lane & 15;
    const int g = lane >> 4;
    const int swz = (lr & 7) << 3;

    const size_t qbase = ((size_t)bh * T + t0) * 64;
    const size_t kbase = (size_t)bh * S * 64;
    const size_t vbase = (size_t)bh * 64;

    // per-lane staging pointers (advance by constants per tile)
    int loff[2];
    const ushort* kp[2];
    const ushort* vp[2];
#pragma unroll
    for (int i = 0; i < 2; ++i) {
        loff[i] = i * 2048 + w * 512 + lane * 8;
        kp[i] = Khi + kbase + loff[i];
        vp[i] = Vhi + (vbase + (loff[i] >> 6)) * S + (loff[i] & 63);
    }

    // precomputed LDS offsets (K-read == V-read form), P write/read offsets
    int rdoff[4][2], pwoff[4], proff[2];
#pragma unroll
    for (int j = 0; j < 4; ++j) {
#pragma unroll
        for (int kk = 0; kk < 2; ++kk)
            rdoff[j][kk] = (j * 16 + lr) * 64 + ((kk * 32 + g * 8) ^ swz);
        pwoff[j] = lr * 64 + ((j * 16 + g * 4) ^ swz);
    }
#pragma unroll
    for (int kk = 0; kk < 2; ++kk)
        proff[kk] = lr * 64 + ((kk * 32 + g * 8) ^ swz);

    // prologue: Q-hi -> sK[1]; first K/V tile -> buf 0
#pragma unroll
    for (int i = 0; i < 2; ++i) GLD_LDS16(Qhi + qbase + loff[i], &sK[1][loff[i]]);
#pragma unroll
    for (int i = 0; i < 2; ++i) {
        GLD_LDS16(kp[i], &sK[0][loff[i]]);
        GLD_LDS16(vp[i], &sV[0][loff[i]]);
        kp[i] += 4096;
        vp[i] += 64;
    }
    __syncthreads();

    bf16x8 qf[2];
#pragma unroll
    for (int kk = 0; kk < 2; ++kk)
        qf[kk] = *reinterpret_cast<const bf16x8*>(
            &sK[1][(w * 16 + lr) * 64 + ((kk * 32 + g * 8) ^ swz)]);
    __syncthreads();  // all Q reads done before buf1 gets overwritten

    ushort* sP = &sPb[w * 1024];  // wave-private

    f32x4 oacc[4];
#pragma unroll
    for (int jd = 0; jd < 4; ++jd) oacc[jd] = (f32x4)0.0f;
    const f32x4 zero4 = (f32x4)0.0f;  // persistent C-in for QK chain starts
    float lpart = 0.0f;  // per-lane partial denominator (own 16 s-slots)

    for (int t = 0; t < NT; ++t) {
        const int bi = t & 1;
        if (t + 1 < NT) {
#pragma unroll
            for (int i = 0; i < 2; ++i) {
                GLD_LDS16(kp[i], &sK[bi ^ 1][loff[i]]);
                GLD_LDS16(vp[i], &sV[bi ^ 1][loff[i]]);
                kp[i] += 4096;
                vp[i] += 64;
            }
        }

        // ---- QK^T swapped, 1-pass: k_hi * q_hi (C-in = zero4) ----
        f32x4 sacc[4];
        __builtin_amdgcn_s_setprio(1);
#pragma unroll
        for (int j = 0; j < 4; ++j) {
            const bf16x8 kh0 = *reinterpret_cast<const bf16x8*>(
                &sK[bi][rdoff[j][0]]);
            const bf16x8 kh1 = *reinterpret_cast<const bf16x8*>(
                &sK[bi][rdoff[j][1]]);
            sacc[j] = __builtin_amdgcn_mfma_f32_16x16x32_bf16(
                kh0, qf[0], zero4, 0, 0, 0);
            sacc[j] = __builtin_amdgcn_mfma_f32_16x16x32_bf16(
                kh1, qf[1], sacc[j], 0, 0, 0);
        }
        __builtin_amdgcn_s_setprio(0);

        // ---- max-free softmax: p = exp2(logit); partial l; pack bf16 ----
        uint32_t wpk[4][2];
#pragma unroll
        for (int j = 0; j < 4; ++j) {
            const float p0 = exp2_raw(sacc[j][0]);
            const float p1 = exp2_raw(sacc[j][1]);
            const float p2 = exp2_raw(sacc[j][2]);
            const float p3 = exp2_raw(sacc[j][3]);
            lpart += (p0 + p1) + (p2 + p3);
            wpk[j][0] = cvt_pk_bf16(p0, p1);
            wpk[j][1] = cvt_pk_bf16(p2, p3);
        }

#pragma unroll
        for (int j = 0; j < 4; ++j)
            *reinterpret_cast<uint2*>(&sP[pwoff[j]]) =
                make_uint2(wpk[j][0], wpk[j][1]);
        asm volatile("s_waitcnt lgkmcnt(0)" ::: "memory");
        __builtin_amdgcn_sched_barrier(0);

        // ---- PV, 1-pass ----
        bf16x8 pf[2];
#pragma unroll
        for (int kk = 0; kk < 2; ++kk)
            pf[kk] = *reinterpret_cast<const bf16x8*>(&sP[proff[kk]]);
        __builtin_amdgcn_s_setprio(1);
#pragma unroll
        for (int jd = 0; jd < 4; ++jd) {
#pragma unroll
            for (int kk = 0; kk < 2; ++kk) {
                const bf16x8 vh = *reinterpret_cast<const bf16x8*>(
                    &sV[bi][rdoff[jd][kk]]);
                oacc[jd] = __builtin_amdgcn_mfma_f32_16x16x32_bf16(
                    pf[kk], vh, oacc[jd], 0, 0, 0);
            }
        }
        __builtin_amdgcn_s_setprio(0);
        __syncthreads();  // drains next tile's loads; protects dbuf reuse
    }

    // ---- epilogue: reduce l across g-groups, write O hi-only ----
    float l = lpart;
    l += __shfl_xor(l, 16);
    l += __shfl_xor(l, 32);

    const int b = bh >> 4, h = bh & 15;
    float linv[4];
#pragma unroll
    for (int r = 0; r < 4; ++r) linv[r] = 1.0f / __shfl(l, g * 4 + r);
#pragma unroll
    for (int r = 0; r < 4; ++r) {
        const int q = t0 + w * 16 + g * 4 + r;
        const size_t rowb = ((size_t)(b * T + q)) * 1024 + h * 64;
#pragma unroll
        for (int jd = 0; jd < 4; ++jd)
            Ohi[rowb + jd * 16 + lr] = f2bf(oacc[jd][r] * linv[r]);
    }
}

// ---------------------------------------------------------------------------
extern "C" void kernel_launch(void* const* d_in, const int* in_sizes, int n_in,
                              void* d_out, int out_size, void* d_ws, size_t ws_size,
                              hipStream_t stream) {
    const int B = 4, T = 1024, S = 2048, D = 1024;

    const float* query = (const float*)d_in[0];
    const float* keyv  = (const float*)d_in[1];
    const float* wq    = (const float*)d_in[2];
    const float* wk    = (const float*)d_in[3];
    const float* wv    = (const float*)d_in[4];
    const float* wo    = (const float*)d_in[5];
    float* out = (float*)d_out;

    const size_t nQ = (size_t)B * T * D;  // 4M
    const size_t nK = (size_t)B * S * D;  // 8M
    const size_t nW = (size_t)D * D;      // 1M

    uint8_t* p = (uint8_t*)d_ws;
    ushort* inq_h = (ushort*)p;  p += nQ * 2;   // 8 MB
    ushort* inkv_h = (ushort*)p; p += nK * 2;   // 16 MB
    ushort* wqh = (ushort*)p;    p += nW * 2;
    ushort* wkh = (ushort*)p;    p += nW * 2;
    ushort* wvh = (ushort*)p;    p += nW * 2;
    ushort* woh = (ushort*)p;    p += nW * 2;
    ushort* wol = (ushort*)p;    p += nW * 2;   // 10 MB
    ushort* aq_h = (ushort*)p;   p += nQ * 2;   // 8 MB (hi only)
    ushort* ak_h = (ushort*)p;   p += nK * 2;   // 16 MB (hi only)
    ushort* avt_h = (ushort*)p;  p += nK * 2;   // 16 MB (hi only)
    ushort* ao_h = (ushort*)p;   p += nQ * 2;   // 8 MB (hi only)
    // total 82 MB

    const dim3 blk(256);

    // 1) all input/weight splits, one launch
    split_all<<<dim3(512, 6), blk, 0, stream>>>(
        query, keyv, wq, wk, wv, wo, inq_h, inkv_h, wqh, wkh, wvh, woh, wol);

    // 2) Q/K/V projections, one batched 1-pass launch (round-13 config)
    qkv_proj<<<dim3(1280), blk, 0, stream>>>(inq_h, inkv_h, wqh, wkh, wvh,
                                             aq_h, ak_h, avt_h);

    // 3) attention (1-D XCD-grouped grid; writes hi-only O)
    attn_mfma<<<dim3((T / 64) * B * N_HEADS), blk, 0, stream>>>(
        aq_h, ak_h, avt_h, ao_h);

    // 4) output projection, 2-pass, 64x128 tiles
    gemm_oproj<<<dim3(D / BN, (B * T) / OBM), blk, 0, stream>>>(
        ao_h, woh, wol, out, B * T, D, D);
}

// Round 17
// 156.423 us; speedup vs baseline: 1.0514x; 1.0030x over previous
//
#include <hip/hip_runtime.h>
#include <cstdint>
#include <cstddef>

#define N_HEADS 16

typedef __attribute__((ext_vector_type(4))) float f32x4;
typedef __attribute__((ext_vector_type(8))) short bf16x8;

// ---------------------------------------------------------------------------
// fp32 -> bf16 helpers (RTN-even, no NaN inputs).
// ---------------------------------------------------------------------------
static __device__ inline ushort f2bf(float x) {
    uint32_t u = __float_as_uint(x);
    uint32_t r = (u + 0x7fffu + ((u >> 16) & 1u)) >> 16;
    return (ushort)r;
}
static __device__ inline float bf2f(ushort h) {
    return __uint_as_float(((uint32_t)h) << 16);
}
static __device__ inline uint32_t cvt_pk_bf16(float lo, float hi) {
    uint32_t r;
    asm("v_cvt_pk_bf16_f32 %0, %1, %2" : "=v"(r) : "v"(lo), "v"(hi));
    return r;
}
// Raw v_exp_f32 (2^x). Inputs are bounded (|x| < ~30) so the OCML denorm
// fixup path is unnecessary; correctness-safe per learn_hip m214-v48.
static __device__ inline float exp2_raw(float x) {
    float r;
    asm("v_exp_f32 %0, %1" : "=v"(r) : "v"(x));
    return r;
}

// ---------------------------------------------------------------------------
// Weight splits only (query/keyv conversion now fused into qkv_proj staging).
// blockIdx.y: 0: wq->hi  1: wk->hi  2: wv->hi  3: wo->hi+lo
// ---------------------------------------------------------------------------
__global__ __launch_bounds__(256) void split_w(
    const float* __restrict__ wq, const float* __restrict__ wk,
    const float* __restrict__ wv, const float* __restrict__ wo,
    ushort* __restrict__ wqh, ushort* __restrict__ wkh,
    ushort* __restrict__ wvh, ushort* __restrict__ woh,
    ushort* __restrict__ wol) {
    const float* x;
    ushort* hi;
    ushort* lo = nullptr;
    switch (blockIdx.y) {
        case 0: x = wq; hi = wqh; break;
        case 1: x = wk; hi = wkh; break;
        case 2: x = wv; hi = wvh; break;
        default: x = wo; hi = woh; lo = wol; break;
    }
    const int n4 = 262144;  // 1M elems / 4
    const int stride = gridDim.x * blockDim.x;
    const bool wlo = (lo != nullptr);
    for (int i = blockIdx.x * blockDim.x + threadIdx.x; i < n4; i += stride) {
        const float4 v = reinterpret_cast<const float4*>(x)[i];
        ushort4 h;
        h.x = f2bf(v.x); h.y = f2bf(v.y); h.z = f2bf(v.z); h.w = f2bf(v.w);
        reinterpret_cast<ushort4*>(hi)[i] = h;
        if (wlo) {
            ushort4 l;
            l.x = f2bf(v.x - bf2f(h.x)); l.y = f2bf(v.y - bf2f(h.y));
            l.z = f2bf(v.z - bf2f(h.z)); l.w = f2bf(v.w - bf2f(h.w));
            reinterpret_cast<ushort4*>(lo)[i] = l;
        }
    }
}

#define BM 128
#define BN 128
#define BK 32

#define GLD_LDS16(gp, lp)                                                  \
    __builtin_amdgcn_global_load_lds(                                      \
        (const __attribute__((address_space(1))) void*)(gp),               \
        (__attribute__((address_space(3))) void*)(lp), 16, 0, 0)

// ---------------------------------------------------------------------------
// Batched Q/K/V projection, single launch (1280 blocks), all 1-pass hi*hi.
// Round 17: A-operand read directly as fp32 (query/keyv) and converted to
// bf16 in-register (cvt_pk_bf16, RTNE) during staging -> eliminates the
// separate query/keyv split pass (~72 MB HBM round-trip). B (weights) stays
// on global_load_lds. Same 128x128 tile / 2-barrier loop / bounds(256,3).
//   [0,256)   seg 0: Q = query @ wq^T, scaled -> attn Q layout [bh][x][64]
//   [256,768) seg 1: K = keyv  @ wk^T -> attn K layout
//   [768,1280)seg 2: V = keyv  @ wv^T -> attn V^T layout [bh][dd][2048]
// Per-segment bijective XCD-grouping for A-panel L2 residency.
// ---------------------------------------------------------------------------
__global__ __launch_bounds__(256, 3) void qkv_proj(
    const float* __restrict__ Aqf, const float* __restrict__ Akvf,
    const ushort* __restrict__ Wqh, const ushort* __restrict__ Wkh,
    const ushort* __restrict__ Wvh, ushort* __restrict__ aq,
    ushort* __restrict__ ak, ushort* __restrict__ avt) {
    constexpr int K = 1024;
    constexpr float QSCALE = 0.18033688011112042f;  // 0.125 * log2(e)
    __shared__ ushort sA[BM * BK];
    __shared__ ushort sB[BN * BK];

    const int bid = blockIdx.x;
    int seg, local, nrow;
    if (bid < 256)      { seg = 0; local = bid;       nrow = 32; }
    else if (bid < 768) { seg = 1; local = bid - 256; nrow = 64; }
    else                { seg = 2; local = bid - 768; nrow = 64; }
    // XCD-grouped bijection within segment (segment size % 8 == 0).
    local = (local & 7) * nrow + (local >> 3);
    const int n0 = (local & 7) * BN;
    const int m0 = (local >> 3) * BM;

    const float* Af  = (seg == 0) ? Aqf : Akvf;
    const ushort* Wh = (seg == 0) ? Wqh : (seg == 1 ? Wkh : Wvh);

    const int tid = threadIdx.x;
    const int lane = tid & 63;
    const int w = tid >> 6;
    const int wm = (w >> 1) * 64;
    const int wn = (w & 1) * 64;

    int srow[2], skq[2];
#pragma unroll
    for (int c = 0; c < 2; ++c) {
        const int row = (w * 2 + c) * 16 + (lane >> 2);
        srow[c] = row;
        skq[c] = (((lane & 3) ^ ((row >> 1) & 3)) << 3);
    }

    f32x4 acc[4][4];
#pragma unroll
    for (int i = 0; i < 4; ++i)
#pragma unroll
        for (int j = 0; j < 4; ++j) acc[i][j] = (f32x4)0.0f;

    const int lr = lane & 15;
    const int kq = lane >> 4;

    for (int k0 = 0; k0 < K; k0 += BK) {
#pragma unroll
        for (int c = 0; c < 2; ++c) {
            // A: fp32 reg-stage -> bf16 (RTNE) -> ds_write_b128 (linear)
            const float* ap =
                Af + (size_t)(m0 + srow[c]) * K + k0 + skq[c];
            const float4 a0 = *reinterpret_cast<const float4*>(ap);
            const float4 a1 = *reinterpret_cast<const float4*>(ap + 4);
            uint4 pk;
            pk.x = cvt_pk_bf16(a0.x, a0.y);
            pk.y = cvt_pk_bf16(a0.z, a0.w);
            pk.z = cvt_pk_bf16(a1.x, a1.y);
            pk.w = cvt_pk_bf16(a1.z, a1.w);
            *reinterpret_cast<uint4*>(&sA[(w * 2 + c) * 512 + lane * 8]) = pk;
            // B: weights via global_load_lds (already bf16)
            GLD_LDS16(Wh + (size_t)(n0 + srow[c]) * K + k0 + skq[c],
                      &sB[(w * 2 + c) * 512]);
        }
        __syncthreads();

        bf16x8 afh[4], bfh[4];
#pragma unroll
        for (int f = 0; f < 4; ++f) {
            const int arow = wm + f * 16 + lr;
            afh[f] = *reinterpret_cast<const bf16x8*>(
                &sA[arow * 32 + ((kq ^ ((arow >> 1) & 3)) << 3)]);
            const int brow = wn + f * 16 + lr;
            bfh[f] = *reinterpret_cast<const bf16x8*>(
                &sB[brow * 32 + ((kq ^ ((brow >> 1) & 3)) << 3)]);
        }
#pragma unroll
        for (int i = 0; i < 4; ++i)
#pragma unroll
            for (int j = 0; j < 4; ++j)
                acc[i][j] = __builtin_amdgcn_mfma_f32_16x16x32_bf16(
                    afh[i], bfh[j], acc[i][j], 0, 0, 0);
        __syncthreads();
    }

    const int cr = (lane >> 4) << 2;
    const int cc = lane & 15;

    if (seg < 2) {  // Q / K layout: [bh][x][64] hi-only, dd ^ ((x&7)<<3)
        const int log2X = (seg == 0) ? 10 : 11;
        const float scale = (seg == 0) ? QSCALE : 1.0f;
        ushort* out = (seg == 0) ? aq : ak;
        const int xm = (1 << log2X) - 1;
#pragma unroll
        for (int i = 0; i < 4; ++i)
#pragma unroll
            for (int j = 0; j < 4; ++j) {
                const int col = n0 + wn + j * 16 + cc;
                const int h = col >> 6, dd = col & 63;
#pragma unroll
                for (int r = 0; r < 4; ++r) {
                    const int mr = m0 + wm + i * 16 + cr + r;
                    const int bb = mr >> log2X;
                    const int x = mr & xm;
                    out[(((size_t)(bb * N_HEADS + h) << log2X) + x) * 64 +
                        (dd ^ ((x & 7) << 3))] = f2bf(acc[i][j][r] * scale);
                }
            }
    } else {  // V^T layout: [bh][dd][2048], s swizzled within 64-blocks
#pragma unroll
        for (int i = 0; i < 4; ++i)
#pragma unroll
            for (int j = 0; j < 4; ++j) {
                const int col = n0 + wn + j * 16 + cc;
                const int h = col >> 6, dd = col & 63;
                const int sb = m0 + wm + i * 16 + cr;
                const int bb = sb >> 11;
                const int sx = sb & 2047;
                ushort4 hv;
#pragma unroll
                for (int r = 0; r < 4; ++r)
                    ((ushort*)&hv)[r] = f2bf(acc[i][j][r]);
                const size_t pos =
                    ((size_t)(bb * N_HEADS + h) * 64 + dd) * 2048 +
                    (sx & ~63) + ((sx & 63) ^ ((dd & 7) << 3));
                *reinterpret_cast<ushort4*>(&avt[pos]) = hv;
            }
    }
}

// ---------------------------------------------------------------------------
// O-projection GEMM: out = AO[M,K] * wo[N,K]^T, 2-pass (A_hi*(W_hi+W_lo)).
// 64x128 tiles -> 512 blocks (2/CU), single-buffer 2-barrier K-loop.
// ---------------------------------------------------------------------------
#define OBM 64
__global__ __launch_bounds__(256, 2) void gemm_oproj(
    const ushort* __restrict__ Ahi, const ushort* __restrict__ Whi,
    const ushort* __restrict__ Wlo, float* __restrict__ Cf, int M, int N,
    int K) {
    __shared__ ushort sA[OBM * BK];    // 4 KB
    __shared__ ushort sB[2][BN * BK];  // 16 KB

    const int tid = threadIdx.x;
    const int lane = tid & 63;
    const int w = tid >> 6;
    const int m0 = blockIdx.y * OBM;
    const int n0 = blockIdx.x * BN;

    // A staging: wave w covers rows [w*16, w*16+16).
    const int sarow = w * 16 + (lane >> 2);
    const int saq = (((lane & 3) ^ ((sarow >> 1) & 3)) << 3);
    // B staging: wave w covers 2 chunks of 16 rows.
    int srow[2], skq[2];
#pragma unroll
    for (int c = 0; c < 2; ++c) {
        const int row = (w * 2 + c) * 16 + (lane >> 2);
        srow[c] = row;
        skq[c] = (((lane & 3) ^ ((row >> 1) & 3)) << 3);
    }

    f32x4 acc[8];
#pragma unroll
    for (int j = 0; j < 8; ++j) acc[j] = (f32x4)0.0f;

    const int lr = lane & 15;
    const int kq = lane >> 4;

    for (int k0 = 0; k0 < K; k0 += BK) {
        GLD_LDS16(Ahi + (size_t)(m0 + sarow) * K + k0 + saq, &sA[w * 512]);
#pragma unroll
        for (int c = 0; c < 2; ++c) {
            const size_t gb = (size_t)(n0 + srow[c]) * K + k0 + skq[c];
            const int loff = (w * 2 + c) * 512;
            GLD_LDS16(Whi + gb, &sB[0][loff]);
            GLD_LDS16(Wlo + gb, &sB[1][loff]);
        }
        __syncthreads();

        const int arow = w * 16 + lr;
        const bf16x8 afh = *reinterpret_cast<const bf16x8*>(
            &sA[arow * 32 + ((kq ^ ((arow >> 1) & 3)) << 3)]);
#pragma unroll
        for (int j = 0; j < 8; ++j) {
            const int brow = j * 16 + lr;
            const int boff = brow * 32 + ((kq ^ ((brow >> 1) & 3)) << 3);
            const bf16x8 bfh = *reinterpret_cast<const bf16x8*>(&sB[0][boff]);
            const bf16x8 bfl = *reinterpret_cast<const bf16x8*>(&sB[1][boff]);
            acc[j] = __builtin_amdgcn_mfma_f32_16x16x32_bf16(afh, bfh,
                                                             acc[j], 0, 0, 0);
            acc[j] = __builtin_amdgcn_mfma_f32_16x16x32_bf16(afh, bfl,
                                                             acc[j], 0, 0, 0);
        }
        __syncthreads();
    }

    const int cr = (lane >> 4) << 2;
    const int cc = lane & 15;
#pragma unroll
    for (int j = 0; j < 8; ++j) {
        float* cp = &Cf[(size_t)(m0 + w * 16 + cr) * N + n0 + j * 16 + cc];
#pragma unroll
        for (int r = 0; r < 4; ++r) cp[(size_t)r * N] = acc[j][r];
    }
}

// ---------------------------------------------------------------------------
// MFMA flash attention, max-free softmax (round-11 version, unchanged).
// ---------------------------------------------------------------------------
__global__ __launch_bounds__(256, 4) void attn_mfma(
    const ushort* __restrict__ Qhi, const ushort* __restrict__ Khi,
    const ushort* __restrict__ Vhi, ushort* __restrict__ Ohi) {
    constexpr int T = 1024, S = 2048, NT = S / 64;
    __shared__ ushort sK[2][4096];  // [buf][s*64+dd]  (hi)
    __shared__ ushort sV[2][4096];  // [buf][dd*64+s]  (hi)
    __shared__ ushort sPb[4096];    // 4 x 2KB wave-private P buffers

    const int tid = threadIdx.x;
    const int lane = tid & 63;
    const int w = tid >> 6;
    const int id = blockIdx.x;
    const int wid = (id & 7) * 128 + (id >> 3);
    const int t0 = (wid & 15) * 64;
    const int bh = wid >> 4;
    const int lr = lane & 15;
    const int g = lane >> 4;
    const int swz = (lr & 7) << 3;

    const size_t qbase = ((size_t)bh * T + t0) * 64;
    const size_t kbase = (size_t)bh * S * 64;
    const size_t vbase = (size_t)bh * 64;

    // per-lane staging pointers (advance by constants per tile)
    int loff[2];
    const ushort* kp[2];
    const ushort* vp[2];
#pragma unroll
    for (int i = 0; i < 2; ++i) {
        loff[i] = i * 2048 + w * 512 + lane * 8;
        kp[i] = Khi + kbase + loff[i];
        vp[i] = Vhi + (vbase + (loff[i] >> 6)) * S + (loff[i] & 63);
    }

    // precomputed LDS offsets (K-read == V-read form), P write/read offsets
    int rdoff[4][2], pwoff[4], proff[2];
#pragma unroll
    for (int j = 0; j < 4; ++j) {
#pragma unroll
        for (int kk = 0; kk < 2; ++kk)
            rdoff[j][kk] = (j * 16 + lr) * 64 + ((kk * 32 + g * 8) ^ swz);
        pwoff[j] = lr * 64 + ((j * 16 + g * 4) ^ swz);
    }
#pragma unroll
    for (int kk = 0; kk < 2; ++kk)
        proff[kk] = lr * 64 + ((kk * 32 + g * 8) ^ swz);

    // prologue: Q-hi -> sK[1]; first K/V tile -> buf 0
#pragma unroll
    for (int i = 0; i < 2; ++i) GLD_LDS16(Qhi + qbase + loff[i], &sK[1][loff[i]]);
#pragma unroll
    for (int i = 0; i < 2; ++i) {
        GLD_LDS16(kp[i], &sK[0][loff[i]]);
        GLD_LDS16(vp[i], &sV[0][loff[i]]);
        kp[i] += 4096;
        vp[i] += 64;
    }
    __syncthreads();

    bf16x8 qf[2];
#pragma unroll
    for (int kk = 0; kk < 2; ++kk)
        qf[kk] = *reinterpret_cast<const bf16x8*>(
            &sK[1][(w * 16 + lr) * 64 + ((kk * 32 + g * 8) ^ swz)]);
    __syncthreads();  // all Q reads done before buf1 gets overwritten

    ushort* sP = &sPb[w * 1024];  // wave-private

    f32x4 oacc[4];
#pragma unroll
    for (int jd = 0; jd < 4; ++jd) oacc[jd] = (f32x4)0.0f;
    const f32x4 zero4 = (f32x4)0.0f;  // persistent C-in for QK chain starts
    float lpart = 0.0f;  // per-lane partial denominator (own 16 s-slots)

    for (int t = 0; t < NT; ++t) {
        const int bi = t & 1;
        if (t + 1 < NT) {
#pragma unroll
            for (int i = 0; i < 2; ++i) {
                GLD_LDS16(kp[i], &sK[bi ^ 1][loff[i]]);
                GLD_LDS16(vp[i], &sV[bi ^ 1][loff[i]]);
                kp[i] += 4096;
                vp[i] += 64;
            }
        }

        // ---- QK^T swapped, 1-pass: k_hi * q_hi (C-in = zero4) ----
        f32x4 sacc[4];
        __builtin_amdgcn_s_setprio(1);
#pragma unroll
        for (int j = 0; j < 4; ++j) {
            const bf16x8 kh0 = *reinterpret_cast<const bf16x8*>(
                &sK[bi][rdoff[j][0]]);
            const bf16x8 kh1 = *reinterpret_cast<const bf16x8*>(
                &sK[bi][rdoff[j][1]]);
            sacc[j] = __builtin_amdgcn_mfma_f32_16x16x32_bf16(
                kh0, qf[0], zero4, 0, 0, 0);
            sacc[j] = __builtin_amdgcn_mfma_f32_16x16x32_bf16(
                kh1, qf[1], sacc[j], 0, 0, 0);
        }
        __builtin_amdgcn_s_setprio(0);

        // ---- max-free softmax: p = exp2(logit); partial l; pack bf16 ----
        uint32_t wpk[4][2];
#pragma unroll
        for (int j = 0; j < 4; ++j) {
            const float p0 = exp2_raw(sacc[j][0]);
            const float p1 = exp2_raw(sacc[j][1]);
            const float p2 = exp2_raw(sacc[j][2]);
            const float p3 = exp2_raw(sacc[j][3]);
            lpart += (p0 + p1) + (p2 + p3);
            wpk[j][0] = cvt_pk_bf16(p0, p1);
            wpk[j][1] = cvt_pk_bf16(p2, p3);
        }

#pragma unroll
        for (int j = 0; j < 4; ++j)
            *reinterpret_cast<uint2*>(&sP[pwoff[j]]) =
                make_uint2(wpk[j][0], wpk[j][1]);
        asm volatile("s_waitcnt lgkmcnt(0)" ::: "memory");
        __builtin_amdgcn_sched_barrier(0);

        // ---- PV, 1-pass ----
        bf16x8 pf[2];
#pragma unroll
        for (int kk = 0; kk < 2; ++kk)
            pf[kk] = *reinterpret_cast<const bf16x8*>(&sP[proff[kk]]);
        __builtin_amdgcn_s_setprio(1);
#pragma unroll
        for (int jd = 0; jd < 4; ++jd) {
#pragma unroll
            for (int kk = 0; kk < 2; ++kk) {
                const bf16x8 vh = *reinterpret_cast<const bf16x8*>(
                    &sV[bi][rdoff[jd][kk]]);
                oacc[jd] = __builtin_amdgcn_mfma_f32_16x16x32_bf16(
                    pf[kk], vh, oacc[jd], 0, 0, 0);
            }
        }
        __builtin_amdgcn_s_setprio(0);
        __syncthreads();  // drains next tile's loads; protects dbuf reuse
    }

    // ---- epilogue: reduce l across g-groups, write O hi-only ----
    float l = lpart;
    l += __shfl_xor(l, 16);
    l += __shfl_xor(l, 32);

    const int b = bh >> 4, h = bh & 15;
    float linv[4];
#pragma unroll
    for (int r = 0; r < 4; ++r) linv[r] = 1.0f / __shfl(l, g * 4 + r);
#pragma unroll
    for (int r = 0; r < 4; ++r) {
        const int q = t0 + w * 16 + g * 4 + r;
        const size_t rowb = ((size_t)(b * T + q)) * 1024 + h * 64;
#pragma unroll
        for (int jd = 0; jd < 4; ++jd)
            Ohi[rowb + jd * 16 + lr] = f2bf(oacc[jd][r] * linv[r]);
    }
}

// ---------------------------------------------------------------------------
extern "C" void kernel_launch(void* const* d_in, const int* in_sizes, int n_in,
                              void* d_out, int out_size, void* d_ws, size_t ws_size,
                              hipStream_t stream) {
    const int B = 4, T = 1024, S = 2048, D = 1024;

    const float* query = (const float*)d_in[0];
    const float* keyv  = (const float*)d_in[1];
    const float* wq    = (const float*)d_in[2];
    const float* wk    = (const float*)d_in[3];
    const float* wv    = (const float*)d_in[4];
    const float* wo    = (const float*)d_in[5];
    float* out = (float*)d_out;

    const size_t nQ = (size_t)B * T * D;  // 4M
    const size_t nK = (size_t)B * S * D;  // 8M
    const size_t nW = (size_t)D * D;      // 1M

    uint8_t* p = (uint8_t*)d_ws;
    ushort* wqh = (ushort*)p;    p += nW * 2;
    ushort* wkh = (ushort*)p;    p += nW * 2;
    ushort* wvh = (ushort*)p;    p += nW * 2;
    ushort* woh = (ushort*)p;    p += nW * 2;
    ushort* wol = (ushort*)p;    p += nW * 2;   // 10 MB
    ushort* aq_h = (ushort*)p;   p += nQ * 2;   // 8 MB (hi only)
    ushort* ak_h = (ushort*)p;   p += nK * 2;   // 16 MB (hi only)
    ushort* avt_h = (ushort*)p;  p += nK * 2;   // 16 MB (hi only)
    ushort* ao_h = (ushort*)p;   p += nQ * 2;   // 8 MB (hi only)
    // total 58 MB

    const dim3 blk(256);

    // 1) weight splits only (query/keyv conversion fused into qkv_proj)
    split_w<<<dim3(128, 4), blk, 0, stream>>>(wq, wk, wv, wo, wqh, wkh, wvh,
                                              woh, wol);

    // 2) Q/K/V projections: fp32-A reg-staged, bf16-W via global_load_lds
    qkv_proj<<<dim3(1280), blk, 0, stream>>>(query, keyv, wqh, wkh, wvh,
                                             aq_h, ak_h, avt_h);

    // 3) attention (1-D XCD-grouped grid; writes hi-only O)
    attn_mfma<<<dim3((T / 64) * B * N_HEADS), blk, 0, stream>>>(
        aq_h, ak_h, avt_h, ao_h);

    // 4) output projection, 2-pass, 64x128 tiles
    gemm_oproj<<<dim3(D / BN, (B * T) / OBM), blk, 0, stream>>>(
        ao_h, woh, wol, out, B * T, D, D);
}